// Round 3
// baseline (624.824 us; speedup 1.0000x reference)
//
#include <hip/hip_runtime.h>
#include <cstdint>
#include <cstddef>

#define B_N  8192
#define FEAT 1024
#define PART 6
#define DC   128
#define OUTC 512

typedef __bf16 bf16;
typedef bf16 bf16x8 __attribute__((ext_vector_type(8)));
typedef bf16 bf16x4 __attribute__((ext_vector_type(4)));
typedef bf16 bf16x2 __attribute__((ext_vector_type(2)));
typedef float f32x4 __attribute__((ext_vector_type(4)));

__device__ __forceinline__ void gload16(const bf16* g, bf16* l) {
  __builtin_amdgcn_global_load_lds(
      (const __attribute__((address_space(1))) void*)g,
      (__attribute__((address_space(3))) void*)l, 16, 0, 0);
}

// ---------- fused prep (weight casts + BN fold) + x transpose ----------
// x [B,1024,6] f32 -> xT [6][B][1024] bf16; plus all weight bf16 casts.
__global__ void k_preptx(const float* __restrict__ x, bf16* __restrict__ xT,
                         const float* __restrict__ w_ps, const float* __restrict__ w_cs,
                         const float* __restrict__ w_up, const float* __restrict__ w_la,
                         const float* __restrict__ g, const float* __restrict__ be,
                         const float* __restrict__ m, const float* __restrict__ v,
                         bf16* __restrict__ wpsb, bf16* __restrict__ wupb,
                         bf16* __restrict__ wlab, float* __restrict__ bnsc,
                         float* __restrict__ bnsh) {
  int t = blockIdx.x * 256 + threadIdx.x;     // [0, 8192*512)
  // transpose part (all threads)
  {
    int b = t >> 9;
    int c0 = (t & 511) << 1;
    const float4* src = (const float4*)(x + ((size_t)b * FEAT + c0) * PART);
    float4 v0 = src[0], v1 = src[1], v2 = src[2];
    float e[12] = {v0.x, v0.y, v0.z, v0.w, v1.x, v1.y, v1.z, v1.w, v2.x, v2.y, v2.z, v2.w};
#pragma unroll
    for (int p = 0; p < PART; ++p) {
      bf16x2 w; w.x = (bf16)e[p]; w.y = (bf16)e[6 + p];
      *(bf16x2*)(xT + ((size_t)p * B_N + b) * FEAT + c0) = w;
    }
  }
  const int NW = PART * DC * FEAT;    // 786432
  const int NL = PART * OUTC * FEAT;  // 3145728
  if (t < NW) {
    int z = t / (DC * FEAT), r = t % (DC * FEAT);
    wpsb[(size_t)(2 * z) * DC * FEAT + r] = (bf16)w_ps[t];
    wpsb[(size_t)(2 * z + 1) * DC * FEAT + r] = (bf16)w_cs[t];
    wupb[t] = (bf16)w_up[t];
  }
  if (t < NL) wlab[t] = (bf16)w_la[t];
  if (t < PART * FEAT) {
    float inv = 1.0f / sqrtf(v[t] + 1e-5f);
    float s = g[t] * inv;
    bnsc[t] = s;
    bnsh[t] = be[t] - m[t] * s;
  }
}

// ---------- tiled MFMA GEMM: Out[z][M,N] = A[z][M,K] @ W[z][N,K]^T, bf16 out ----------
// BM=BN=128, BK=32 double-buffered (32 KB LDS), 4 waves 2x2.
// Chunk-major LDS [4][128][8]: conflict-free ds_read_b128, linear gload_lds dest.
// Raw s_barrier + counted vmcnt(4): stage(kt+1) in flight across barriers (T3/T4-lite).
// EPI 0: lrelu (GEMM1 ps|cs N=256) | 1: BN+lrelu+resid (GEMM2) | 2: raw (GEMM3)
template <int EPI, int K, int N, int TM, int TN, int NZ>
__global__ __launch_bounds__(256, 3) void k_gemm(
    const bf16* __restrict__ Abase, const bf16* __restrict__ Wbase,
    bf16* __restrict__ Out,
    const float* __restrict__ bnsc, const float* __restrict__ bnsh,
    const bf16* __restrict__ resid) {
  constexpr int NT = K / 32;
  __shared__ bf16 As[2][4096];
  __shared__ bf16 Ws[2][4096];
  const int tid = threadIdx.x;
  const int wv = tid >> 6, lane = tid & 63;
  const int wr = wv >> 1, wc = wv & 1;
  const int l = lane & 15, hh = lane >> 4;

  // XCD-chunked bijective swizzle: nwg = TM*TN*NZ, multiple of 8; tn-fastest.
  constexpr int NWG = TM * TN * NZ;
  constexpr int QC = NWG / 8;
  int bid = blockIdx.x;
  int lid = (bid & 7) * QC + (bid >> 3);
  int tn = lid % TN;
  int tm = (lid / TN) % TM;
  int z = lid / (TN * TM);

  const bf16* A = Abase + (size_t)z * B_N * K + (size_t)tm * 128 * K;
  const bf16* W = Wbase + (size_t)z * N * K + (size_t)tn * 128 * K;

  f32x4 acc[4][4] = {};

  auto STAGE = [&](int buf, int kt) {
#pragma unroll
    for (int it = 0; it < 2; ++it) {
      int gidx = it * 4 + wv;                 // 0..7
      int row = (gidx & 1) * 64 + lane;
      int chunk = gidx >> 1;                  // 0..3
      int slot0 = it * 256 + wv * 64;         // wave-uniform
      gload16(A + (size_t)row * K + kt * 32 + chunk * 8, &As[buf][slot0 * 8]);
      gload16(W + (size_t)row * K + kt * 32 + chunk * 8, &Ws[buf][slot0 * 8]);
    }
  };

  STAGE(0, 0);
  for (int kt = 0; kt < NT; ++kt) {
    int cur = kt & 1;
    if (kt + 1 < NT) {
      STAGE(cur ^ 1, kt + 1);
      asm volatile("s_waitcnt vmcnt(4)" ::: "memory");  // my cur loads done, next 4 in flight
    } else {
      asm volatile("s_waitcnt vmcnt(0)" ::: "memory");
    }
    __builtin_amdgcn_sched_barrier(0);
    __builtin_amdgcn_s_barrier();               // all waves staged cur
    __builtin_amdgcn_sched_barrier(0);

    bf16x8 af[4], wf[4];
#pragma unroll
    for (int mi = 0; mi < 4; ++mi)
      af[mi] = *(const bf16x8*)&As[cur][(hh * 128 + wr * 64 + mi * 16 + l) * 8];
#pragma unroll
    for (int ni = 0; ni < 4; ++ni)
      wf[ni] = *(const bf16x8*)&Ws[cur][(hh * 128 + wc * 64 + ni * 16 + l) * 8];
#pragma unroll
    for (int mi = 0; mi < 4; ++mi)
#pragma unroll
      for (int ni = 0; ni < 4; ++ni)
        acc[mi][ni] = __builtin_amdgcn_mfma_f32_16x16x32_bf16(af[mi], wf[ni], acc[mi][ni], 0, 0, 0);

    __builtin_amdgcn_sched_barrier(0);
    asm volatile("" ::: "memory");
    __builtin_amdgcn_s_barrier();               // all reads of cur in regs -> re-stageable
    __builtin_amdgcn_sched_barrier(0);
  }

#pragma unroll
  for (int mi = 0; mi < 4; ++mi)
#pragma unroll
    for (int ni = 0; ni < 4; ++ni)
#pragma unroll
      for (int r = 0; r < 4; ++r) {
        int row = tm * 128 + wr * 64 + mi * 16 + hh * 4 + r;
        int col = tn * 128 + wc * 64 + ni * 16 + l;
        float v = acc[mi][ni][r];
        if constexpr (EPI == 0) {
          v = v >= 0.f ? v : 0.25f * v;
        } else if constexpr (EPI == 1) {
          v = v * bnsc[z * N + col] + bnsh[z * N + col];
          v = v >= 0.f ? v : 0.25f * v;
          v += (float)resid[((size_t)z * B_N + row) * N + col];
        }
        Out[((size_t)z * B_N + row) * N + col] = (bf16)v;
      }
}

// ---------- attention: 2 rows per wave (32 lanes each), 5-round butterfly ----------
// psb bf16 [6][B][256]: cols 0-127 = ps, 128-255 = cs. Lane sl=lane&31 holds k=4*sl..+3.
__global__ __launch_bounds__(256) void k_att(const bf16* __restrict__ psb,
                                             bf16* __restrict__ embT) {
  int wv = threadIdx.x >> 6, lane = threadIdx.x & 63;
  int half = lane >> 5, sl = lane & 31;
  int b = blockIdx.x * 8 + wv * 2 + half;
  float p[6][4], c[6][4];
#pragma unroll
  for (int pp = 0; pp < 6; ++pp) {
    const bf16* base = psb + ((size_t)pp * B_N + b) * 256;
    bf16x4 vp = *(const bf16x4*)(base + 4 * sl);
    bf16x4 vc = *(const bf16x4*)(base + 128 + 4 * sl);
#pragma unroll
    for (int j = 0; j < 4; ++j) { p[pp][j] = (float)vp[j]; c[pp][j] = (float)vc[j]; }
  }
  float red[48];
#pragma unroll
  for (int pp = 0; pp < 6; ++pp) {
    float np = 0.f, nc = 0.f;
#pragma unroll
    for (int j = 0; j < 4; ++j) { np = fmaf(p[pp][j], p[pp][j], np); nc = fmaf(c[pp][j], c[pp][j], nc); }
    red[pp] = np; red[6 + pp] = nc;
  }
#pragma unroll
  for (int pp = 0; pp < 6; ++pp)
#pragma unroll
    for (int q = 0; q < 6; ++q) {
      float d = 0.f;
#pragma unroll
      for (int j = 0; j < 4; ++j) d = fmaf(p[pp][j], c[q][j], d);
      red[12 + pp * 6 + q] = d;
    }
#pragma unroll
  for (int m = 1; m < 32; m <<= 1)
#pragma unroll
    for (int i = 0; i < 48; ++i)
      red[i] += __shfl_xor(red[i], m, 64);

  float inp[6], inc[6];
#pragma unroll
  for (int pp = 0; pp < 6; ++pp) {
    inp[pp] = 1.f / (sqrtf(red[pp]) + 1e-8f);
    inc[pp] = 1.f / (sqrtf(red[6 + pp]) + 1e-8f);
  }
  float att[6][6];
#pragma unroll
  for (int pp = 0; pp < 6; ++pp)
#pragma unroll
    for (int q = 0; q < 6; ++q)
      att[pp][q] = red[12 + pp * 6 + q] * inp[pp] * inc[q] + (pp == q ? -1000000.f : 0.f);
#pragma unroll
  for (int q = 0; q < 6; ++q) {
    float mx = att[0][q];
#pragma unroll
    for (int pp = 1; pp < 6; ++pp) mx = fmaxf(mx, att[pp][q]);
    float e[6], s = 0.f;
#pragma unroll
    for (int pp = 0; pp < 6; ++pp) { e[pp] = __expf(att[pp][q] - mx); s += e[pp]; }
    float is = 1.f / s;
#pragma unroll
    for (int pp = 0; pp < 6; ++pp) att[pp][q] = e[pp] * is;
  }
#pragma unroll
  for (int q = 0; q < 6; ++q) {
    float e[4] = {0.f, 0.f, 0.f, 0.f};
#pragma unroll
    for (int pp = 0; pp < 6; ++pp) {
      float a = att[pp][q] * inp[pp];
#pragma unroll
      for (int j = 0; j < 4; ++j) e[j] = fmaf(p[pp][j], a, e[j]);
    }
    bf16x4 w;
#pragma unroll
    for (int j = 0; j < 4; ++j) w[j] = (bf16)e[j];
    *(bf16x4*)(embT + ((size_t)q * B_N + b) * DC + 4 * sl) = w;
  }
}

// outT [6][B][512] bf16 -> out [B,512,6] f32
__global__ void k_transpose_out(const bf16* __restrict__ oT, float* __restrict__ out) {
  int t = blockIdx.x * 256 + threadIdx.x;     // [0, 8192*256)
  int b = t >> 8;
  int o0 = (t & 255) << 1;
  float a[6], c[6];
#pragma unroll
  for (int p = 0; p < 6; ++p) {
    bf16x2 v = *(const bf16x2*)(oT + ((size_t)p * B_N + b) * OUTC + o0);
    a[p] = (float)v.x; c[p] = (float)v.y;
  }
  float* dst = out + ((size_t)b * OUTC + o0) * PART;
  float4 w0 = {a[0], a[1], a[2], a[3]};
  float4 w1 = {a[4], a[5], c[0], c[1]};
  float4 w2 = {c[2], c[3], c[4], c[5]};
  ((float4*)dst)[0] = w0; ((float4*)dst)[1] = w1; ((float4*)dst)[2] = w2;
}

extern "C" void kernel_launch(void* const* d_in, const int* in_sizes, int n_in,
                              void* d_out, int out_size, void* d_ws, size_t ws_size,
                              hipStream_t stream) {
  const float* x    = (const float*)d_in[0];
  const float* w_ps = (const float*)d_in[1];
  const float* w_cs = (const float*)d_in[2];
  const float* w_up = (const float*)d_in[3];
  const float* gam  = (const float*)d_in[4];
  const float* bet  = (const float*)d_in[5];
  const float* mea  = (const float*)d_in[6];
  const float* var  = (const float*)d_in[7];
  const float* w_la = (const float*)d_in[8];

  char* ws = (char*)d_ws;
  size_t off = 0;
  auto alloc = [&](size_t bytes) { void* p = ws + off; off += (bytes + 255) & ~(size_t)255; return p; };

  bf16* xT    = (bf16*)alloc((size_t)PART * B_N * FEAT * 2);       // 100.7 MB (reused as outT)
  bf16* wpsb  = (bf16*)alloc((size_t)PART * 256 * FEAT * 2);       // [6][256][1024] ps|cs
  bf16* wupb  = (bf16*)alloc((size_t)PART * FEAT * DC * 2);
  bf16* wlab  = (bf16*)alloc((size_t)PART * OUTC * FEAT * 2);
  float* bnsc = (float*)alloc((size_t)PART * FEAT * 4);
  float* bnsh = (float*)alloc((size_t)PART * FEAT * 4);
  bf16* psb   = (bf16*)alloc((size_t)PART * B_N * 256 * 2);        // 25.2 MB
  bf16* embT  = (bf16*)alloc((size_t)PART * B_N * DC * 2);
  bf16* emb2T = (bf16*)alloc((size_t)PART * B_N * FEAT * 2);
  bf16* outT  = xT;                                                // alias: xT dead after GEMM2

  k_preptx<<<B_N * 512 / 256, 256, 0, stream>>>(
      x, xT, w_ps, w_cs, w_up, w_la, gam, bet, mea, var, wpsb, wupb, wlab, bnsc, bnsh);

  // GEMM1: [ps|cs] = lrelu(x_p @ [Wps;Wcs]^T), N=256
  k_gemm<0, FEAT, 256, 64, 2, 6><<<768, 256, 0, stream>>>(
      xT, wpsb, psb, nullptr, nullptr, nullptr);
  // attention
  k_att<<<B_N / 8, 256, 0, stream>>>(psb, embT);
  // GEMM2: emb2 = x + lrelu(BN(emb_att @ Wup^T))
  k_gemm<1, DC, FEAT, 64, 8, 6><<<3072, 256, 0, stream>>>(
      embT, wupb, emb2T, bnsc, bnsh, xT);
  // GEMM3: outT = emb2 @ Wla^T
  k_gemm<2, FEAT, OUTC, 64, 4, 6><<<1536, 256, 0, stream>>>(
      emb2T, wlab, outT, nullptr, nullptr, nullptr);
  k_transpose_out<<<B_N * 256 / 256, 256, 0, stream>>>(outT, (float*)d_out);
}